// Round 1
// baseline (1737.477 us; speedup 1.0000x reference)
//
#include <hip/hip_runtime.h>
#include <cstdint>

#define N_NODES 100000
#define N_EDGES 1600000
#define R_REL   5
#define NBASIS  2
#define B_START 512

// ---------------- CSR build ----------------

__global__ void k_zero_int(int* p, int n) {
    int i = blockIdx.x * blockDim.x + threadIdx.x;
    if (i < n) p[i] = 0;
}

__global__ void k_hist(const int* __restrict__ ei, const int* __restrict__ et,
                       int* __restrict__ cnt) {
    int e = blockIdx.x * blockDim.x + threadIdx.x;
    if (e < N_EDGES) {
        int dst = ei[N_EDGES + e];
        int t   = et[e];
        atomicAdd(&cnt[dst * R_REL + t], 1);
    }
}

__global__ void k_norm(const int* __restrict__ cnt, float* __restrict__ normf) {
    int i = blockIdx.x * blockDim.x + threadIdx.x;
    if (i < N_NODES * R_REL) {
        int c = cnt[i];
        normf[i] = 1.0f / (float)(c > 0 ? c : 1);
    }
}

__global__ void k_scan1(const int* __restrict__ cnt, int* __restrict__ off,
                        int* __restrict__ bsum) {
    __shared__ int s[256];
    int t = threadIdx.x;
    int n = blockIdx.x * 256 + t;
    int deg = 0;
    if (n < N_NODES) {
#pragma unroll
        for (int r = 0; r < R_REL; r++) deg += cnt[n * R_REL + r];
    }
    s[t] = deg;
    __syncthreads();
    for (int o = 1; o < 256; o <<= 1) {
        int v = (t >= o) ? s[t - o] : 0;
        __syncthreads();
        s[t] += v;
        __syncthreads();
    }
    if (n < N_NODES) off[n] = s[t] - deg;   // local exclusive prefix
    if (t == 255) bsum[blockIdx.x] = s[t];  // block total
}

__global__ void k_scan2(int* bsum, int nb) {
    __shared__ int s[512];
    int t = threadIdx.x;
    int v = (t < nb) ? bsum[t] : 0;
    s[t] = v;
    __syncthreads();
    for (int o = 1; o < 512; o <<= 1) {
        int u = (t >= o) ? s[t - o] : 0;
        __syncthreads();
        s[t] += u;
        __syncthreads();
    }
    if (t < nb) bsum[t] = s[t] - v;  // exclusive
}

__global__ void k_scan3(int* __restrict__ off, int* __restrict__ cur,
                        const int* __restrict__ bsum) {
    int t = threadIdx.x;
    int n = blockIdx.x * 256 + t;
    if (n < N_NODES) {
        int v = off[n] + bsum[blockIdx.x];
        off[n] = v;
        cur[n] = v;
    }
    if (n == 0) off[N_NODES] = N_EDGES;
}

__global__ void k_fill(const int* __restrict__ ei, const int* __restrict__ et,
                       int* __restrict__ cur, int* __restrict__ edges) {
    int e = blockIdx.x * blockDim.x + threadIdx.x;
    if (e < N_EDGES) {
        int src = ei[e];
        int dst = ei[N_EDGES + e];
        int t   = et[e];
        int slot = atomicAdd(&cur[dst], 1);
        edges[slot] = src | (t << 20);
    }
}

// ---------------- RGCN layer (fused msg = h[src] @ W[et]) ----------------
// One 32-lane half-wave per destination node; lane = output channel.

template <int IN>
__global__ __launch_bounds__(256) void k_rgcn(
    const float* __restrict__ h_in, float* __restrict__ h_out,
    const float* __restrict__ basis, const float* __restrict__ comp,
    const float* __restrict__ root, const float* __restrict__ bias,
    const int* __restrict__ off, const int* __restrict__ edges,
    const float* __restrict__ normf) {
    __shared__ float Wl[R_REL * IN * 32];
    __shared__ float Rl[IN * 32];
    int tid = threadIdx.x;
    for (int idx = tid; idx < R_REL * IN * 32; idx += 256) {
        int r = idx / (IN * 32);
        int rem = idx - r * (IN * 32);
        Wl[idx] = comp[r * NBASIS] * basis[rem] +
                  comp[r * NBASIS + 1] * basis[IN * 32 + rem];
    }
    for (int idx = tid; idx < IN * 32; idx += 256) Rl[idx] = root[idx];
    __syncthreads();

    int lane = tid & 31;
    int sub  = tid >> 5;
    int n = blockIdx.x * 8 + sub;
    if (n >= N_NODES) return;

    float nr0 = normf[n * R_REL + 0];
    float nr1 = normf[n * R_REL + 1];
    float nr2 = normf[n * R_REL + 2];
    float nr3 = normf[n * R_REL + 3];
    float nr4 = normf[n * R_REL + 4];

    float acc = bias[lane];
    // root transform
    float hn = (lane < IN) ? h_in[n * IN + lane] : 0.f;
#pragma unroll
    for (int i = 0; i < IN; i++)
        acc += __shfl(hn, i, 32) * Rl[i * 32 + lane];

    int e0 = off[n], e1 = off[n + 1];
    for (int base = e0; base < e1; base += 32) {
        int m = (base + lane < e1) ? edges[base + lane] : 0;
        int kmax = e1 - base;
        if (kmax > 32) kmax = 32;
        for (int j = 0; j < kmax; j++) {
            int mj  = __shfl(m, j, 32);
            int src = mj & 0xFFFFF;
            int etj = ((unsigned)mj) >> 20;
            float hs = (lane < IN) ? h_in[src * IN + lane] : 0.f;
            const float* Wp = &Wl[etj * IN * 32];
            float msg = 0.f;
#pragma unroll
            for (int i = 0; i < IN; i++)
                msg += __shfl(hs, i, 32) * Wp[i * 32 + lane];
            float nv = (etj == 0) ? nr0
                     : (etj == 1) ? nr1
                     : (etj == 2) ? nr2
                     : (etj == 3) ? nr3 : nr4;
            acc += msg * nv;
        }
    }
    h_out[n * 32 + lane] = tanhf(acc);
}

// ---------------- start-node row save + MLP head ----------------

__global__ void k_save(const float* __restrict__ h, const int* __restrict__ start,
                       float* __restrict__ sav) {
    int t = blockIdx.x * blockDim.x + threadIdx.x;
    if (t < B_START * 32) {
        int b = t >> 5, ln = t & 31;
        sav[t] = h[start[b] * 32 + ln];
    }
}

__global__ __launch_bounds__(128) void k_mlp(
    const float* __restrict__ sav, const float* __restrict__ w1,
    const float* __restrict__ b1, const float* __restrict__ w2,
    const float* __restrict__ b2, float* __restrict__ out) {
    __shared__ float cvec[128];
    __shared__ float hb[128];
    __shared__ float lg[8];
    int b = blockIdx.x, t = threadIdx.x;
    cvec[t] = sav[(t >> 5) * (B_START * 32) + b * 32 + (t & 31)];
    __syncthreads();
    float a = b1[t];
#pragma unroll 8
    for (int k = 0; k < 128; k++) a += cvec[k] * w1[k * 128 + t];
    hb[t] = fmaxf(a, 0.f);
    __syncthreads();
    if (t < 5) {
        float a2 = b2[t];
        for (int k = 0; k < 128; k++) a2 += hb[k] * w2[k * 5 + t];
        lg[t] = a2;
    }
    __syncthreads();
    if (t < 5) {
        float m = lg[0];
        for (int j = 1; j < 5; j++) m = fmaxf(m, lg[j]);
        float s = 0.f;
        for (int j = 0; j < 5; j++) s += expf(lg[j] - m);
        out[b * 5 + t] = lg[t] - m - logf(s);
    }
}

// ---------------- launch ----------------

extern "C" void kernel_launch(void* const* d_in, const int* in_sizes, int n_in,
                              void* d_out, int out_size, void* d_ws, size_t ws_size,
                              hipStream_t stream) {
    const float* x      = (const float*)d_in[0];
    const int*   ei     = (const int*)d_in[1];
    const int*   etype  = (const int*)d_in[2];
    const int*   start  = (const int*)d_in[3];
    const float* basis0 = (const float*)d_in[4];
    const float* comp0  = (const float*)d_in[5];
    const float* root0  = (const float*)d_in[6];
    const float* bias0  = (const float*)d_in[7];
    const float* basis  = (const float*)d_in[8];
    const float* comp   = (const float*)d_in[9];
    const float* root   = (const float*)d_in[10];
    const float* bias   = (const float*)d_in[11];
    const float* w1     = (const float*)d_in[12];
    const float* b1     = (const float*)d_in[13];
    const float* w2     = (const float*)d_in[14];
    const float* b2     = (const float*)d_in[15];
    float* out = (float*)d_out;

    char* p = (char*)d_ws;
    auto alloc = [&](size_t bytes) -> void* {
        void* r = (void*)p;
        p += (bytes + 255) & ~(size_t)255;
        return r;
    };
    int*   off   = (int*)alloc((N_NODES + 1) * 4);
    int*   cur   = (int*)alloc(N_NODES * 4);
    int*   cnt   = (int*)alloc(N_NODES * R_REL * 4);
    int*   edges = (int*)alloc(N_EDGES * 4);
    int*   bsum  = (int*)alloc(512 * 4);
    float* normf = (float*)alloc(N_NODES * R_REL * 4);
    float* hA    = (float*)alloc((size_t)N_NODES * 32 * 4);
    float* hB    = (float*)alloc((size_t)N_NODES * 32 * 4);
    float* sav   = (float*)alloc(4 * B_START * 32 * 4);

    int nbScan = (N_NODES + 255) / 256;  // 391

    k_zero_int<<<(N_NODES * R_REL + 255) / 256, 256, 0, stream>>>(cnt, N_NODES * R_REL);
    k_hist<<<(N_EDGES + 255) / 256, 256, 0, stream>>>(ei, etype, cnt);
    k_scan1<<<nbScan, 256, 0, stream>>>(cnt, off, bsum);
    k_scan2<<<1, 512, 0, stream>>>(bsum, nbScan);
    k_scan3<<<nbScan, 256, 0, stream>>>(off, cur, bsum);
    k_norm<<<(N_NODES * R_REL + 255) / 256, 256, 0, stream>>>(cnt, normf);
    k_fill<<<(N_EDGES + 255) / 256, 256, 0, stream>>>(ei, etype, cur, edges);

    // layer 0: in=4
    k_rgcn<4><<<12500, 256, 0, stream>>>(x, hA, basis0, comp0, root0, bias0,
                                         off, edges, normf);
    k_save<<<64, 256, 0, stream>>>(hA, start, sav);
    // layers 1..3: in=32
    k_rgcn<32><<<12500, 256, 0, stream>>>(hA, hB, basis, comp, root, bias,
                                          off, edges, normf);
    k_save<<<64, 256, 0, stream>>>(hB, start, sav + 16384);
    k_rgcn<32><<<12500, 256, 0, stream>>>(hB, hA, basis + 2048, comp + 10,
                                          root + 1024, bias + 32, off, edges, normf);
    k_save<<<64, 256, 0, stream>>>(hA, start, sav + 32768);
    k_rgcn<32><<<12500, 256, 0, stream>>>(hA, hB, basis + 4096, comp + 20,
                                          root + 2048, bias + 64, off, edges, normf);
    k_save<<<64, 256, 0, stream>>>(hB, start, sav + 49152);

    k_mlp<<<B_START, 128, 0, stream>>>(sav, w1, b1, w2, b2, out);
}

// Round 2
// 630.956 us; speedup vs baseline: 2.7537x; 2.7537x over previous
//
#include <hip/hip_runtime.h>
#include <cstdint>

#define N_NODES 100000
#define N_EDGES 1600000
#define R_REL   5
#define NBASIS  2
#define B_START 512

// ---------------- CSR build ----------------

__global__ void k_zero_int(int* p, int n) {
    int i = blockIdx.x * blockDim.x + threadIdx.x;
    if (i < n) p[i] = 0;
}

__global__ void k_hist(const int* __restrict__ ei, const int* __restrict__ et,
                       int* __restrict__ cnt) {
    int e = blockIdx.x * blockDim.x + threadIdx.x;
    if (e < N_EDGES) {
        int dst = ei[N_EDGES + e];
        int t   = et[e];
        atomicAdd(&cnt[dst * R_REL + t], 1);
    }
}

__global__ void k_norm(const int* __restrict__ cnt, float* __restrict__ normf) {
    int i = blockIdx.x * blockDim.x + threadIdx.x;
    if (i < N_NODES * R_REL) {
        int c = cnt[i];
        normf[i] = 1.0f / (float)(c > 0 ? c : 1);
    }
}

__global__ void k_scan1(const int* __restrict__ cnt, int* __restrict__ off,
                        int* __restrict__ bsum) {
    __shared__ int s[256];
    int t = threadIdx.x;
    int n = blockIdx.x * 256 + t;
    int deg = 0;
    if (n < N_NODES) {
#pragma unroll
        for (int r = 0; r < R_REL; r++) deg += cnt[n * R_REL + r];
    }
    s[t] = deg;
    __syncthreads();
    for (int o = 1; o < 256; o <<= 1) {
        int v = (t >= o) ? s[t - o] : 0;
        __syncthreads();
        s[t] += v;
        __syncthreads();
    }
    if (n < N_NODES) off[n] = s[t] - deg;   // local exclusive prefix
    if (t == 255) bsum[blockIdx.x] = s[t];  // block total
}

__global__ void k_scan2(int* bsum, int nb) {
    __shared__ int s[512];
    int t = threadIdx.x;
    int v = (t < nb) ? bsum[t] : 0;
    s[t] = v;
    __syncthreads();
    for (int o = 1; o < 512; o <<= 1) {
        int u = (t >= o) ? s[t - o] : 0;
        __syncthreads();
        s[t] += u;
        __syncthreads();
    }
    if (t < nb) bsum[t] = s[t] - v;  // exclusive
}

__global__ void k_scan3(int* __restrict__ off, int* __restrict__ cur,
                        const int* __restrict__ bsum) {
    int t = threadIdx.x;
    int n = blockIdx.x * 256 + t;
    if (n < N_NODES) {
        int v = off[n] + bsum[blockIdx.x];
        off[n] = v;
        cur[n] = v;
    }
    if (n == 0) off[N_NODES] = N_EDGES;
}

__global__ void k_fill(const int* __restrict__ ei, const int* __restrict__ et,
                       int* __restrict__ cur, int* __restrict__ edges,
                       const float* __restrict__ normf, float* __restrict__ enorm) {
    int e = blockIdx.x * blockDim.x + threadIdx.x;
    if (e < N_EDGES) {
        int src = ei[e];
        int dst = ei[N_EDGES + e];
        int t   = et[e];
        int slot = atomicAdd(&cur[dst], 1);
        edges[slot] = src | (t << 20);
        enorm[slot] = normf[dst * R_REL + t];
    }
}

// ---------------- per-layer node transform: y0=h@B0, y1=h@B1, yr=h@root ----
// W columns held in registers; 32-lane group per node, grid-stride.

template <int IN>
__global__ __launch_bounds__(256) void k_xform(
    const float* __restrict__ h_in, float2* __restrict__ y01,
    float* __restrict__ yr, const float* __restrict__ basis,
    const float* __restrict__ root) {
    int tid  = threadIdx.x;
    int lane = tid & 31;
    int sub  = tid >> 5;
    int g    = blockIdx.x * 8 + sub;   // 256 blocks * 8 groups = 2048 groups
    float w0[IN], w1[IN], wr[IN];
#pragma unroll
    for (int i = 0; i < IN; i++) {
        w0[i] = basis[i * 32 + lane];
        w1[i] = basis[IN * 32 + i * 32 + lane];
        wr[i] = root[i * 32 + lane];
    }
    for (int n = g; n < N_NODES; n += 2048) {
        float hn = (lane < IN) ? h_in[n * IN + lane] : 0.f;
        float a0 = 0.f, a1 = 0.f, ar = 0.f;
#pragma unroll
        for (int i = 0; i < IN; i++) {
            float v = __shfl(hn, i, 32);
            a0 += v * w0[i];
            a1 += v * w1[i];
            ar += v * wr[i];
        }
        y01[n * 32 + lane] = make_float2(a0, a1);
        yr[n * 32 + lane]  = ar;
    }
}

// ---------------- edge aggregation: acc += nv*(c0*y0[src] + c1*y1[src]) ----

__global__ __launch_bounds__(256) void k_edge(
    const float2* __restrict__ y01, const float* __restrict__ yr,
    float* __restrict__ h_out, const float* __restrict__ compL,
    const float* __restrict__ biasL, const int* __restrict__ off,
    const int* __restrict__ edges, const float* __restrict__ enorm) {
    __shared__ __align__(8) float Cl[2 * R_REL];
    int tid = threadIdx.x;
    if (tid < 2 * R_REL) Cl[tid] = compL[tid];
    __syncthreads();
    int lane = tid & 31;
    int sub  = tid >> 5;
    int n = blockIdx.x * 8 + sub;
    if (n >= N_NODES) return;

    float acc = yr[n * 32 + lane] + biasL[lane];
    int e0 = off[n], e1 = off[n + 1];
    for (int base = e0; base < e1; base += 32) {
        int idx = base + lane;
        bool vld = idx < e1;
        int   m  = vld ? edges[idx] : 0;
        float nv = vld ? enorm[idx] : 0.f;
        int kmax = e1 - base;
        if (kmax > 32) kmax = 32;
        int kk = (kmax + 3) & ~3;
        for (int j = 0; j < kk; j += 4) {
            int m0 = __shfl(m, j, 32),     m1 = __shfl(m, j + 1, 32);
            int m2 = __shfl(m, j + 2, 32), m3 = __shfl(m, j + 3, 32);
            float v0 = __shfl(nv, j, 32),     v1 = __shfl(nv, j + 1, 32);
            float v2 = __shfl(nv, j + 2, 32), v3 = __shfl(nv, j + 3, 32);
            float2 g0 = y01[(m0 & 0xFFFFF) * 32 + lane];
            float2 g1 = y01[(m1 & 0xFFFFF) * 32 + lane];
            float2 g2 = y01[(m2 & 0xFFFFF) * 32 + lane];
            float2 g3 = y01[(m3 & 0xFFFFF) * 32 + lane];
            int t0 = ((unsigned)m0) >> 20, t1 = ((unsigned)m1) >> 20;
            int t2 = ((unsigned)m2) >> 20, t3 = ((unsigned)m3) >> 20;
            acc += v0 * (Cl[t0 * 2] * g0.x + Cl[t0 * 2 + 1] * g0.y);
            acc += v1 * (Cl[t1 * 2] * g1.x + Cl[t1 * 2 + 1] * g1.y);
            acc += v2 * (Cl[t2 * 2] * g2.x + Cl[t2 * 2 + 1] * g2.y);
            acc += v3 * (Cl[t3 * 2] * g3.x + Cl[t3 * 2 + 1] * g3.y);
        }
    }
    h_out[n * 32 + lane] = tanhf(acc);
}

// ---------------- start-node row save + MLP head ----------------

__global__ void k_save(const float* __restrict__ h, const int* __restrict__ start,
                       float* __restrict__ sav) {
    int t = blockIdx.x * blockDim.x + threadIdx.x;
    if (t < B_START * 32) {
        int b = t >> 5, ln = t & 31;
        sav[t] = h[start[b] * 32 + ln];
    }
}

__global__ __launch_bounds__(128) void k_mlp(
    const float* __restrict__ sav, const float* __restrict__ w1,
    const float* __restrict__ b1, const float* __restrict__ w2,
    const float* __restrict__ b2, float* __restrict__ out) {
    __shared__ float cvec[128];
    __shared__ float hb[128];
    __shared__ float lg[8];
    int b = blockIdx.x, t = threadIdx.x;
    cvec[t] = sav[(t >> 5) * (B_START * 32) + b * 32 + (t & 31)];
    __syncthreads();
    float a = b1[t];
#pragma unroll 8
    for (int k = 0; k < 128; k++) a += cvec[k] * w1[k * 128 + t];
    hb[t] = fmaxf(a, 0.f);
    __syncthreads();
    if (t < 5) {
        float a2 = b2[t];
        for (int k = 0; k < 128; k++) a2 += hb[k] * w2[k * 5 + t];
        lg[t] = a2;
    }
    __syncthreads();
    if (t < 5) {
        float m = lg[0];
        for (int j = 1; j < 5; j++) m = fmaxf(m, lg[j]);
        float s = 0.f;
        for (int j = 0; j < 5; j++) s += expf(lg[j] - m);
        out[b * 5 + t] = lg[t] - m - logf(s);
    }
}

// ---------------- launch ----------------

extern "C" void kernel_launch(void* const* d_in, const int* in_sizes, int n_in,
                              void* d_out, int out_size, void* d_ws, size_t ws_size,
                              hipStream_t stream) {
    const float* x      = (const float*)d_in[0];
    const int*   ei     = (const int*)d_in[1];
    const int*   etype  = (const int*)d_in[2];
    const int*   start  = (const int*)d_in[3];
    const float* basis0 = (const float*)d_in[4];
    const float* comp0  = (const float*)d_in[5];
    const float* root0  = (const float*)d_in[6];
    const float* bias0  = (const float*)d_in[7];
    const float* basis  = (const float*)d_in[8];
    const float* comp   = (const float*)d_in[9];
    const float* root   = (const float*)d_in[10];
    const float* bias   = (const float*)d_in[11];
    const float* w1     = (const float*)d_in[12];
    const float* b1     = (const float*)d_in[13];
    const float* w2     = (const float*)d_in[14];
    const float* b2     = (const float*)d_in[15];
    float* out = (float*)d_out;

    char* p = (char*)d_ws;
    auto alloc = [&](size_t bytes) -> void* {
        void* r = (void*)p;
        p += (bytes + 255) & ~(size_t)255;
        return r;
    };
    int*    off   = (int*)alloc((N_NODES + 1) * 4);
    int*    cur   = (int*)alloc(N_NODES * 4);
    int*    cnt   = (int*)alloc(N_NODES * R_REL * 4);
    int*    edges = (int*)alloc((size_t)N_EDGES * 4);
    float*  enorm = (float*)alloc((size_t)N_EDGES * 4);
    int*    bsum  = (int*)alloc(512 * 4);
    float*  normf = (float*)alloc(N_NODES * R_REL * 4);
    float*  h     = (float*)alloc((size_t)N_NODES * 32 * 4);
    float2* y01   = (float2*)alloc((size_t)N_NODES * 32 * 8);
    float*  yr    = (float*)alloc((size_t)N_NODES * 32 * 4);
    float*  sav   = (float*)alloc(4 * B_START * 32 * 4);

    int nbScan = (N_NODES + 255) / 256;  // 391

    k_zero_int<<<(N_NODES * R_REL + 255) / 256, 256, 0, stream>>>(cnt, N_NODES * R_REL);
    k_hist<<<(N_EDGES + 255) / 256, 256, 0, stream>>>(ei, etype, cnt);
    k_norm<<<(N_NODES * R_REL + 255) / 256, 256, 0, stream>>>(cnt, normf);
    k_scan1<<<nbScan, 256, 0, stream>>>(cnt, off, bsum);
    k_scan2<<<1, 512, 0, stream>>>(bsum, nbScan);
    k_scan3<<<nbScan, 256, 0, stream>>>(off, cur, bsum);
    k_fill<<<(N_EDGES + 255) / 256, 256, 0, stream>>>(ei, etype, cur, edges, normf, enorm);

    // layer 0 (in=4)
    k_xform<4><<<256, 256, 0, stream>>>(x, y01, yr, basis0, root0);
    k_edge<<<12500, 256, 0, stream>>>(y01, yr, h, comp0, bias0, off, edges, enorm);
    k_save<<<64, 256, 0, stream>>>(h, start, sav);
    // layers 1..3 (in=32)
    for (int l = 0; l < 3; l++) {
        k_xform<32><<<256, 256, 0, stream>>>(h, y01, yr,
                                             basis + (size_t)l * 2048,
                                             root + (size_t)l * 1024);
        k_edge<<<12500, 256, 0, stream>>>(y01, yr, h, comp + l * 10,
                                          bias + l * 32, off, edges, enorm);
        k_save<<<64, 256, 0, stream>>>(h, start, sav + (l + 1) * 16384);
    }

    k_mlp<<<B_START, 128, 0, stream>>>(sav, w1, b1, w2, b2, out);
}

// Round 3
// 607.480 us; speedup vs baseline: 2.8601x; 1.0386x over previous
//
#include <hip/hip_runtime.h>
#include <cstdint>

#define N_NODES 100000
#define N_EDGES 1600000
#define R_REL   5
#define NBASIS  2
#define B_START 512

// ---------------- CSR build ----------------

__global__ void k_zero_int(int* p, int n) {
    int i = blockIdx.x * blockDim.x + threadIdx.x;
    if (i < n) p[i] = 0;
}

__global__ void k_hist(const int* __restrict__ ei, const int* __restrict__ et,
                       int* __restrict__ cnt) {
    int e = blockIdx.x * blockDim.x + threadIdx.x;
    if (e < N_EDGES) {
        int dst = ei[N_EDGES + e];
        int t   = et[e];
        atomicAdd(&cnt[dst * R_REL + t], 1);
    }
}

// local scan over node degrees + per-(node,rel) mean norm
__global__ void k_scan1(const int* __restrict__ cnt, int* __restrict__ off,
                        int* __restrict__ bsum, float* __restrict__ normf) {
    __shared__ int s[256];
    int t = threadIdx.x;
    int n = blockIdx.x * 256 + t;
    int deg = 0;
    if (n < N_NODES) {
#pragma unroll
        for (int r = 0; r < R_REL; r++) {
            int c = cnt[n * R_REL + r];
            deg += c;
            normf[n * R_REL + r] = 1.0f / (float)(c > 0 ? c : 1);
        }
    }
    s[t] = deg;
    __syncthreads();
    for (int o = 1; o < 256; o <<= 1) {
        int v = (t >= o) ? s[t - o] : 0;
        __syncthreads();
        s[t] += v;
        __syncthreads();
    }
    if (n < N_NODES) off[n] = s[t] - deg;   // local exclusive prefix
    if (t == 255) bsum[blockIdx.x] = s[t];  // block total
}

__global__ void k_scan2(int* bsum, int nb) {
    __shared__ int s[512];
    int t = threadIdx.x;
    int v = (t < nb) ? bsum[t] : 0;
    s[t] = v;
    __syncthreads();
    for (int o = 1; o < 512; o <<= 1) {
        int u = (t >= o) ? s[t - o] : 0;
        __syncthreads();
        s[t] += u;
        __syncthreads();
    }
    if (t < nb) bsum[t] = s[t] - v;  // exclusive
}

__global__ void k_scan3(int* __restrict__ off, int* __restrict__ cur,
                        const int* __restrict__ bsum) {
    int t = threadIdx.x;
    int n = blockIdx.x * 256 + t;
    if (n < N_NODES) {
        int v = off[n] + bsum[blockIdx.x];
        off[n] = v;
        cur[n] = v;
    }
    if (n == 0) off[N_NODES] = N_EDGES;
}

// single 8B packed scatter: {src | et<<20, float_bits(norm)}
__global__ void k_fill(const int* __restrict__ ei, const int* __restrict__ et,
                       int* __restrict__ cur, int2* __restrict__ packed,
                       const float* __restrict__ normf) {
    int e = blockIdx.x * blockDim.x + threadIdx.x;
    if (e < N_EDGES) {
        int src = ei[e];
        int dst = ei[N_EDGES + e];
        int t   = et[e];
        int slot = atomicAdd(&cur[dst], 1);
        float nv = normf[dst * R_REL + t];
        packed[slot] = make_int2(src | (t << 20), __float_as_int(nv));
    }
}

// ---------------- per-layer edge weights: ew = nv * (c0[et], c1[et]) -------

__global__ void k_prep(const int2* __restrict__ packed,
                       const float* __restrict__ compL,
                       float2* __restrict__ ew) {
    __shared__ float C[2 * R_REL];
    if (threadIdx.x < 2 * R_REL) C[threadIdx.x] = compL[threadIdx.x];
    __syncthreads();
    int e = blockIdx.x * blockDim.x + threadIdx.x;
    if (e < N_EDGES) {
        int2 pk = packed[e];
        int t = ((unsigned)pk.x) >> 20;
        float nv = __int_as_float(pk.y);
        ew[e] = make_float2(nv * C[t * 2], nv * C[t * 2 + 1]);
    }
}

// ---------------- per-layer node transform ---------------------------------
// y0=h@B0, y1=h@B1 -> y01 ;  h := h@root + bias (in-place per-row, race-free)

template <int IN>
__global__ __launch_bounds__(256) void k_xform(
    const float* __restrict__ h_in, float* __restrict__ h_io,
    float2* __restrict__ y01, const float* __restrict__ basis,
    const float* __restrict__ root, const float* __restrict__ biasL) {
    int tid  = threadIdx.x;
    int lane = tid & 31;
    int sub  = tid >> 5;
    int g    = blockIdx.x * 8 + sub;   // 1024 blocks * 8 groups = 8192 groups
    float w0[IN], w1[IN], wr[IN];
#pragma unroll
    for (int i = 0; i < IN; i++) {
        w0[i] = basis[i * 32 + lane];
        w1[i] = basis[IN * 32 + i * 32 + lane];
        wr[i] = root[i * 32 + lane];
    }
    float bv = biasL[lane];
    for (int n = g; n < N_NODES; n += 8192) {
        float hn = (lane < IN) ? h_in[n * IN + lane] : 0.f;
        float a0 = 0.f, a1 = 0.f, ar = bv;
#pragma unroll
        for (int i = 0; i < IN; i++) {
            float v = __shfl(hn, i, 32);
            a0 += v * w0[i];
            a1 += v * w1[i];
            ar += v * wr[i];
        }
        y01[n * 32 + lane] = make_float2(a0, a1);
        h_io[n * 32 + lane] = ar;
    }
}

// ---------------- edge aggregation: h[n] = tanh(h[n] + sum ew.(y0,y1)) -----

__global__ __launch_bounds__(256) void k_edge(
    const float2* __restrict__ y01, float* __restrict__ h,
    const int2* __restrict__ packed, const float2* __restrict__ ew,
    const int* __restrict__ off) {
    int tid  = threadIdx.x;
    int lane = tid & 31;
    int sub  = tid >> 5;
    int n = blockIdx.x * 8 + sub;
    if (n >= N_NODES) return;

    float acc = h[n * 32 + lane];
    int e0 = off[n], e1 = off[n + 1];
    for (int base = e0; base < e1; base += 32) {
        int idx = base + lane;
        bool vld = idx < e1;
        int    m = vld ? packed[idx].x : 0;
        float2 w = vld ? ew[idx] : make_float2(0.f, 0.f);
        int kmax = e1 - base;
        if (kmax > 32) kmax = 32;
        int kk = (kmax + 7) & ~7;
        for (int j = 0; j < kk; j += 8) {
            int s0 = __shfl(m, j + 0, 32) & 0xFFFFF;
            int s1 = __shfl(m, j + 1, 32) & 0xFFFFF;
            int s2 = __shfl(m, j + 2, 32) & 0xFFFFF;
            int s3 = __shfl(m, j + 3, 32) & 0xFFFFF;
            int s4 = __shfl(m, j + 4, 32) & 0xFFFFF;
            int s5 = __shfl(m, j + 5, 32) & 0xFFFFF;
            int s6 = __shfl(m, j + 6, 32) & 0xFFFFF;
            int s7 = __shfl(m, j + 7, 32) & 0xFFFFF;
            float2 g0 = y01[s0 * 32 + lane];
            float2 g1 = y01[s1 * 32 + lane];
            float2 g2 = y01[s2 * 32 + lane];
            float2 g3 = y01[s3 * 32 + lane];
            float2 g4 = y01[s4 * 32 + lane];
            float2 g5 = y01[s5 * 32 + lane];
            float2 g6 = y01[s6 * 32 + lane];
            float2 g7 = y01[s7 * 32 + lane];
            float x0 = __shfl(w.x, j + 0, 32), z0 = __shfl(w.y, j + 0, 32);
            float x1 = __shfl(w.x, j + 1, 32), z1 = __shfl(w.y, j + 1, 32);
            float x2 = __shfl(w.x, j + 2, 32), z2 = __shfl(w.y, j + 2, 32);
            float x3 = __shfl(w.x, j + 3, 32), z3 = __shfl(w.y, j + 3, 32);
            float x4 = __shfl(w.x, j + 4, 32), z4 = __shfl(w.y, j + 4, 32);
            float x5 = __shfl(w.x, j + 5, 32), z5 = __shfl(w.y, j + 5, 32);
            float x6 = __shfl(w.x, j + 6, 32), z6 = __shfl(w.y, j + 6, 32);
            float x7 = __shfl(w.x, j + 7, 32), z7 = __shfl(w.y, j + 7, 32);
            acc += x0 * g0.x + z0 * g0.y;
            acc += x1 * g1.x + z1 * g1.y;
            acc += x2 * g2.x + z2 * g2.y;
            acc += x3 * g3.x + z3 * g3.y;
            acc += x4 * g4.x + z4 * g4.y;
            acc += x5 * g5.x + z5 * g5.y;
            acc += x6 * g6.x + z6 * g6.y;
            acc += x7 * g7.x + z7 * g7.y;
        }
    }
    h[n * 32 + lane] = tanhf(acc);
}

// ---------------- start-node row save + MLP head ----------------

__global__ void k_save(const float* __restrict__ h, const int* __restrict__ start,
                       float* __restrict__ sav) {
    int t = blockIdx.x * blockDim.x + threadIdx.x;
    if (t < B_START * 32) {
        int b = t >> 5, ln = t & 31;
        sav[t] = h[start[b] * 32 + ln];
    }
}

__global__ __launch_bounds__(128) void k_mlp(
    const float* __restrict__ sav, const float* __restrict__ w1,
    const float* __restrict__ b1, const float* __restrict__ w2,
    const float* __restrict__ b2, float* __restrict__ out) {
    __shared__ float cvec[128];
    __shared__ float hb[128];
    __shared__ float lg[8];
    int b = blockIdx.x, t = threadIdx.x;
    cvec[t] = sav[(t >> 5) * (B_START * 32) + b * 32 + (t & 31)];
    __syncthreads();
    float a = b1[t];
#pragma unroll 8
    for (int k = 0; k < 128; k++) a += cvec[k] * w1[k * 128 + t];
    hb[t] = fmaxf(a, 0.f);
    __syncthreads();
    if (t < 5) {
        float a2 = b2[t];
        for (int k = 0; k < 128; k++) a2 += hb[k] * w2[k * 5 + t];
        lg[t] = a2;
    }
    __syncthreads();
    if (t < 5) {
        float m = lg[0];
        for (int j = 1; j < 5; j++) m = fmaxf(m, lg[j]);
        float s = 0.f;
        for (int j = 0; j < 5; j++) s += expf(lg[j] - m);
        out[b * 5 + t] = lg[t] - m - logf(s);
    }
}

// ---------------- launch ----------------

extern "C" void kernel_launch(void* const* d_in, const int* in_sizes, int n_in,
                              void* d_out, int out_size, void* d_ws, size_t ws_size,
                              hipStream_t stream) {
    const float* x      = (const float*)d_in[0];
    const int*   ei     = (const int*)d_in[1];
    const int*   etype  = (const int*)d_in[2];
    const int*   start  = (const int*)d_in[3];
    const float* basis0 = (const float*)d_in[4];
    const float* comp0  = (const float*)d_in[5];
    const float* root0  = (const float*)d_in[6];
    const float* bias0  = (const float*)d_in[7];
    const float* basis  = (const float*)d_in[8];
    const float* comp   = (const float*)d_in[9];
    const float* root   = (const float*)d_in[10];
    const float* bias   = (const float*)d_in[11];
    const float* w1     = (const float*)d_in[12];
    const float* b1     = (const float*)d_in[13];
    const float* w2     = (const float*)d_in[14];
    const float* b2     = (const float*)d_in[15];
    float* out = (float*)d_out;

    char* p = (char*)d_ws;
    auto alloc = [&](size_t bytes) -> void* {
        void* r = (void*)p;
        p += (bytes + 255) & ~(size_t)255;
        return r;
    };
    int*    off    = (int*)alloc((N_NODES + 1) * 4);
    int*    cur    = (int*)alloc(N_NODES * 4);
    int*    cnt    = (int*)alloc(N_NODES * R_REL * 4);
    int2*   packed = (int2*)alloc((size_t)N_EDGES * 8);
    float2* ew     = (float2*)alloc((size_t)N_EDGES * 8);
    int*    bsum   = (int*)alloc(512 * 4);
    float*  normf  = (float*)alloc(N_NODES * R_REL * 4);
    float*  h      = (float*)alloc((size_t)N_NODES * 32 * 4);
    float2* y01    = (float2*)alloc((size_t)N_NODES * 32 * 8);
    float*  sav    = (float*)alloc(4 * B_START * 32 * 4);

    int nbScan = (N_NODES + 255) / 256;  // 391

    k_zero_int<<<(N_NODES * R_REL + 255) / 256, 256, 0, stream>>>(cnt, N_NODES * R_REL);
    k_hist<<<(N_EDGES + 255) / 256, 256, 0, stream>>>(ei, etype, cnt);
    k_scan1<<<nbScan, 256, 0, stream>>>(cnt, off, bsum, normf);
    k_scan2<<<1, 512, 0, stream>>>(bsum, nbScan);
    k_scan3<<<nbScan, 256, 0, stream>>>(off, cur, bsum);
    k_fill<<<(N_EDGES + 255) / 256, 256, 0, stream>>>(ei, etype, cur, packed, normf);

    // layer 0 (in=4)
    k_prep<<<(N_EDGES + 255) / 256, 256, 0, stream>>>(packed, comp0, ew);
    k_xform<4><<<1024, 256, 0, stream>>>(x, h, y01, basis0, root0, bias0);
    k_edge<<<12500, 256, 0, stream>>>(y01, h, packed, ew, off);
    k_save<<<64, 256, 0, stream>>>(h, start, sav);
    // layers 1..3 (in=32)
    for (int l = 0; l < 3; l++) {
        k_prep<<<(N_EDGES + 255) / 256, 256, 0, stream>>>(packed, comp + l * 10, ew);
        k_xform<32><<<1024, 256, 0, stream>>>(h, h, y01,
                                              basis + (size_t)l * 2048,
                                              root + (size_t)l * 1024,
                                              bias + l * 32);
        k_edge<<<12500, 256, 0, stream>>>(y01, h, packed, ew, off);
        k_save<<<64, 256, 0, stream>>>(h, start, sav + (l + 1) * 16384);
    }

    k_mlp<<<B_START, 128, 0, stream>>>(sav, w1, b1, w2, b2, out);
}

// Round 4
// 491.877 us; speedup vs baseline: 3.5323x; 1.2350x over previous
//
#include <hip/hip_runtime.h>
#include <cstdint>

#define N_NODES 100000
#define N_EDGES 1600000
#define R_REL   5
#define NBASIS  2
#define B_START 512
#define NPART   8
#define PART_SZ 12500   // 8 * 12500 = 100000

__device__ __forceinline__ unsigned short f2bf(float f) {
    unsigned u = __float_as_uint(f);
    unsigned r = (u + 0x7FFF + ((u >> 16) & 1)) >> 16;  // RNE
    return (unsigned short)r;
}

// ---------------- CSR build ----------------

__global__ void k_zero_int(int* p, int n) {
    int i = blockIdx.x * blockDim.x + threadIdx.x;
    if (i < n) p[i] = 0;
}

// XCD-partitioned histogram: part p (blocks with blockIdx%8==p, i.e. one XCD
// under round-robin dispatch) handles dst in [p*12500,(p+1)*12500) so cnt
// lines are written from a single XCD's L2.
__global__ void k_hist(const int* __restrict__ ei, const int* __restrict__ et,
                       int* __restrict__ cnt) {
    int part = blockIdx.x & 7;
    int bid  = blockIdx.x >> 3;
    int nb   = gridDim.x >> 3;
    for (int e = bid * 256 + threadIdx.x; e < N_EDGES; e += nb * 256) {
        int dst = ei[N_EDGES + e];
        if (dst / PART_SZ == part) {
            int t = et[e];
            atomicAdd(&cnt[dst * R_REL + t], 1);
        }
    }
}

// local scan over node degrees + per-(node,rel) mean norm
__global__ void k_scan1(const int* __restrict__ cnt, int* __restrict__ off,
                        int* __restrict__ bsum, float* __restrict__ normf) {
    __shared__ int s[256];
    int t = threadIdx.x;
    int n = blockIdx.x * 256 + t;
    int deg = 0;
    if (n < N_NODES) {
#pragma unroll
        for (int r = 0; r < R_REL; r++) {
            int c = cnt[n * R_REL + r];
            deg += c;
            normf[n * R_REL + r] = 1.0f / (float)(c > 0 ? c : 1);
        }
    }
    s[t] = deg;
    __syncthreads();
    for (int o = 1; o < 256; o <<= 1) {
        int v = (t >= o) ? s[t - o] : 0;
        __syncthreads();
        s[t] += v;
        __syncthreads();
    }
    if (n < N_NODES) off[n] = s[t] - deg;
    if (t == 255) bsum[blockIdx.x] = s[t];
}

__global__ void k_scan2(int* bsum, int nb) {
    __shared__ int s[512];
    int t = threadIdx.x;
    int v = (t < nb) ? bsum[t] : 0;
    s[t] = v;
    __syncthreads();
    for (int o = 1; o < 512; o <<= 1) {
        int u = (t >= o) ? s[t - o] : 0;
        __syncthreads();
        s[t] += u;
        __syncthreads();
    }
    if (t < nb) bsum[t] = s[t] - v;
}

__global__ void k_scan3(int* __restrict__ off, int* __restrict__ cur,
                        const int* __restrict__ bsum) {
    int t = threadIdx.x;
    int n = blockIdx.x * 256 + t;
    if (n < N_NODES) {
        int v = off[n] + bsum[blockIdx.x];
        off[n] = v;
        cur[n] = v;
    }
    if (n == 0) off[N_NODES] = N_EDGES;
}

// XCD-partitioned CSR fill: packed slot lines written by a single XCD.
// packed = {src | et<<20, float_bits(norm)}
__global__ void k_fill(const int* __restrict__ ei, const int* __restrict__ et,
                       int* __restrict__ cur, int2* __restrict__ packed,
                       const float* __restrict__ normf) {
    int part = blockIdx.x & 7;
    int bid  = blockIdx.x >> 3;
    int nb   = gridDim.x >> 3;
    for (int e = bid * 256 + threadIdx.x; e < N_EDGES; e += nb * 256) {
        int dst = ei[N_EDGES + e];
        if (dst / PART_SZ == part) {
            int src = ei[e];
            int t   = et[e];
            int slot = atomicAdd(&cur[dst], 1);
            float nv = normf[dst * R_REL + t];
            packed[slot] = make_int2(src | (t << 20), __float_as_int(nv));
        }
    }
}

// ---------------- per-layer node transform ---------------------------------
// y5[r][n][c] = bf16( comp[r,0]*(h@B0) + comp[r,1]*(h@B1) )   (5 planes)
// h := h@root + bias   (in-place per-row, race-free)

template <int IN>
__global__ __launch_bounds__(256) void k_xform(
    const float* __restrict__ h_in, float* __restrict__ h_io,
    unsigned short* __restrict__ y5, const float* __restrict__ basis,
    const float* __restrict__ root, const float* __restrict__ biasL,
    const float* __restrict__ compL) {
    int tid  = threadIdx.x;
    int lane = tid & 31;
    int sub  = tid >> 5;
    int g    = blockIdx.x * 8 + sub;   // 1024 blocks * 8 = 8192 groups
    float w0[IN], w1[IN], wr[IN];
#pragma unroll
    for (int i = 0; i < IN; i++) {
        w0[i] = basis[i * 32 + lane];
        w1[i] = basis[IN * 32 + i * 32 + lane];
        wr[i] = root[i * 32 + lane];
    }
    float c0[R_REL], c1[R_REL];
#pragma unroll
    for (int r = 0; r < R_REL; r++) {
        c0[r] = compL[r * NBASIS + 0];
        c1[r] = compL[r * NBASIS + 1];
    }
    float bv = biasL[lane];
    for (int n = g; n < N_NODES; n += 8192) {
        float hn = (lane < IN) ? h_in[n * IN + lane] : 0.f;
        float a0 = 0.f, a1 = 0.f, ar = bv;
#pragma unroll
        for (int i = 0; i < IN; i++) {
            float v = __shfl(hn, i, 32);
            a0 += v * w0[i];
            a1 += v * w1[i];
            ar += v * wr[i];
        }
#pragma unroll
        for (int r = 0; r < R_REL; r++)
            y5[(size_t)r * N_NODES * 32 + n * 32 + lane] = f2bf(c0[r] * a0 + c1[r] * a1);
        h_io[n * 32 + lane] = ar;
    }
}

// ---------------- edge aggregation: h[n] = tanh(h[n] + sum nv*y5[et][src]) -

__global__ __launch_bounds__(256) void k_edge(
    const unsigned short* __restrict__ y5, float* __restrict__ h,
    const int2* __restrict__ packed, const int* __restrict__ off) {
    int tid  = threadIdx.x;
    int lane = tid & 31;
    int sub  = tid >> 5;
    int n = blockIdx.x * 8 + sub;
    if (n >= N_NODES) return;

    float acc = h[n * 32 + lane];
    int e0 = off[n], e1 = off[n + 1];
    for (int base = e0; base < e1; base += 32) {
        int idx = base + lane;
        bool vld = idx < e1;
        int2 pk  = vld ? packed[idx] : make_int2(0, 0);
        int   m  = pk.x;
        float nv = __int_as_float(pk.y);   // 0 bits -> 0.0f for pad lanes
        int kmax = e1 - base;
        if (kmax > 32) kmax = 32;
        int kk = (kmax + 7) & ~7;
        for (int j = 0; j < kk; j += 8) {
            int m0 = __shfl(m, j + 0, 32), m1 = __shfl(m, j + 1, 32);
            int m2 = __shfl(m, j + 2, 32), m3 = __shfl(m, j + 3, 32);
            int m4 = __shfl(m, j + 4, 32), m5 = __shfl(m, j + 5, 32);
            int m6 = __shfl(m, j + 6, 32), m7 = __shfl(m, j + 7, 32);
            // row = et*N + src ; addr = row*32 + lane (ushort)
            unsigned r0 = ((unsigned)m0 >> 20) * N_NODES + (m0 & 0xFFFFF);
            unsigned r1 = ((unsigned)m1 >> 20) * N_NODES + (m1 & 0xFFFFF);
            unsigned r2 = ((unsigned)m2 >> 20) * N_NODES + (m2 & 0xFFFFF);
            unsigned r3 = ((unsigned)m3 >> 20) * N_NODES + (m3 & 0xFFFFF);
            unsigned r4 = ((unsigned)m4 >> 20) * N_NODES + (m4 & 0xFFFFF);
            unsigned r5 = ((unsigned)m5 >> 20) * N_NODES + (m5 & 0xFFFFF);
            unsigned r6 = ((unsigned)m6 >> 20) * N_NODES + (m6 & 0xFFFFF);
            unsigned r7 = ((unsigned)m7 >> 20) * N_NODES + (m7 & 0xFFFFF);
            unsigned short u0 = y5[(size_t)r0 * 32 + lane];
            unsigned short u1 = y5[(size_t)r1 * 32 + lane];
            unsigned short u2 = y5[(size_t)r2 * 32 + lane];
            unsigned short u3 = y5[(size_t)r3 * 32 + lane];
            unsigned short u4 = y5[(size_t)r4 * 32 + lane];
            unsigned short u5 = y5[(size_t)r5 * 32 + lane];
            unsigned short u6 = y5[(size_t)r6 * 32 + lane];
            unsigned short u7 = y5[(size_t)r7 * 32 + lane];
            float v0 = __shfl(nv, j + 0, 32), v1 = __shfl(nv, j + 1, 32);
            float v2 = __shfl(nv, j + 2, 32), v3 = __shfl(nv, j + 3, 32);
            float v4 = __shfl(nv, j + 4, 32), v5 = __shfl(nv, j + 5, 32);
            float v6 = __shfl(nv, j + 6, 32), v7 = __shfl(nv, j + 7, 32);
            acc += v0 * __uint_as_float((unsigned)u0 << 16);
            acc += v1 * __uint_as_float((unsigned)u1 << 16);
            acc += v2 * __uint_as_float((unsigned)u2 << 16);
            acc += v3 * __uint_as_float((unsigned)u3 << 16);
            acc += v4 * __uint_as_float((unsigned)u4 << 16);
            acc += v5 * __uint_as_float((unsigned)u5 << 16);
            acc += v6 * __uint_as_float((unsigned)u6 << 16);
            acc += v7 * __uint_as_float((unsigned)u7 << 16);
        }
    }
    h[n * 32 + lane] = tanhf(acc);
}

// ---------------- start-node row save + MLP head ----------------

__global__ void k_save(const float* __restrict__ h, const int* __restrict__ start,
                       float* __restrict__ sav) {
    int t = blockIdx.x * blockDim.x + threadIdx.x;
    if (t < B_START * 32) {
        int b = t >> 5, ln = t & 31;
        sav[t] = h[start[b] * 32 + ln];
    }
}

__global__ __launch_bounds__(128) void k_mlp(
    const float* __restrict__ sav, const float* __restrict__ w1,
    const float* __restrict__ b1, const float* __restrict__ w2,
    const float* __restrict__ b2, float* __restrict__ out) {
    __shared__ float cvec[128];
    __shared__ float hb[128];
    __shared__ float lg[8];
    int b = blockIdx.x, t = threadIdx.x;
    cvec[t] = sav[(t >> 5) * (B_START * 32) + b * 32 + (t & 31)];
    __syncthreads();
    float a = b1[t];
#pragma unroll 8
    for (int k = 0; k < 128; k++) a += cvec[k] * w1[k * 128 + t];
    hb[t] = fmaxf(a, 0.f);
    __syncthreads();
    if (t < 5) {
        float a2 = b2[t];
        for (int k = 0; k < 128; k++) a2 += hb[k] * w2[k * 5 + t];
        lg[t] = a2;
    }
    __syncthreads();
    if (t < 5) {
        float m = lg[0];
        for (int j = 1; j < 5; j++) m = fmaxf(m, lg[j]);
        float s = 0.f;
        for (int j = 0; j < 5; j++) s += expf(lg[j] - m);
        out[b * 5 + t] = lg[t] - m - logf(s);
    }
}

// ---------------- launch ----------------

extern "C" void kernel_launch(void* const* d_in, const int* in_sizes, int n_in,
                              void* d_out, int out_size, void* d_ws, size_t ws_size,
                              hipStream_t stream) {
    const float* x      = (const float*)d_in[0];
    const int*   ei     = (const int*)d_in[1];
    const int*   etype  = (const int*)d_in[2];
    const int*   start  = (const int*)d_in[3];
    const float* basis0 = (const float*)d_in[4];
    const float* comp0  = (const float*)d_in[5];
    const float* root0  = (const float*)d_in[6];
    const float* bias0  = (const float*)d_in[7];
    const float* basis  = (const float*)d_in[8];
    const float* comp   = (const float*)d_in[9];
    const float* root   = (const float*)d_in[10];
    const float* bias   = (const float*)d_in[11];
    const float* w1     = (const float*)d_in[12];
    const float* b1     = (const float*)d_in[13];
    const float* w2     = (const float*)d_in[14];
    const float* b2     = (const float*)d_in[15];
    float* out = (float*)d_out;

    char* p = (char*)d_ws;
    auto alloc = [&](size_t bytes) -> void* {
        void* r = (void*)p;
        p += (bytes + 255) & ~(size_t)255;
        return r;
    };
    int*            off    = (int*)alloc((N_NODES + 1) * 4);
    int*            cur    = (int*)alloc(N_NODES * 4);
    int*            cnt    = (int*)alloc(N_NODES * R_REL * 4);
    int2*           packed = (int2*)alloc((size_t)N_EDGES * 8);
    int*            bsum   = (int*)alloc(512 * 4);
    float*          normf  = (float*)alloc(N_NODES * R_REL * 4);
    float*          h      = (float*)alloc((size_t)N_NODES * 32 * 4);
    unsigned short* y5     = (unsigned short*)alloc((size_t)R_REL * N_NODES * 32 * 2);
    float*          sav    = (float*)alloc(4 * B_START * 32 * 4);

    int nbScan = (N_NODES + 255) / 256;  // 391

    k_zero_int<<<(N_NODES * R_REL + 255) / 256, 256, 0, stream>>>(cnt, N_NODES * R_REL);
    k_hist<<<8 * 784, 256, 0, stream>>>(ei, etype, cnt);
    k_scan1<<<nbScan, 256, 0, stream>>>(cnt, off, bsum, normf);
    k_scan2<<<1, 512, 0, stream>>>(bsum, nbScan);
    k_scan3<<<nbScan, 256, 0, stream>>>(off, cur, bsum);
    k_fill<<<8 * 784, 256, 0, stream>>>(ei, etype, cur, packed, normf);

    // layer 0 (in=4)
    k_xform<4><<<1024, 256, 0, stream>>>(x, h, y5, basis0, root0, bias0, comp0);
    k_edge<<<12500, 256, 0, stream>>>(y5, h, packed, off);
    k_save<<<64, 256, 0, stream>>>(h, start, sav);
    // layers 1..3 (in=32)
    for (int l = 0; l < 3; l++) {
        k_xform<32><<<1024, 256, 0, stream>>>(h, h, y5,
                                              basis + (size_t)l * 2048,
                                              root + (size_t)l * 1024,
                                              bias + l * 32,
                                              comp + l * 10);
        k_edge<<<12500, 256, 0, stream>>>(y5, h, packed, off);
        k_save<<<64, 256, 0, stream>>>(h, start, sav + (l + 1) * 16384);
    }

    k_mlp<<<B_START, 128, 0, stream>>>(sav, w1, b1, w2, b2, out);
}